// Round 6
// baseline (1617.054 us; speedup 1.0000x reference)
//
#include <hip/hip_runtime.h>
#include <hip/hip_fp16.h>
#include <math.h>

// ---------------------------------------------------------------------------
// RNN: h_{t+1} = relu(x_t @ W_in^T + h_t @ W_hh^T + b_hh + noise_t*scale)
// outputs: hidden_list [128,256,1024] f32, output_list [128,256,128] f32,
//          h_final [128,1024] f32 (concatenated flat in d_out)
//
// R6: R5 (tag-in-data dataflow + cooperative LDS staging) + DUAL-DOMAIN
// LATENCY MULTIPLEXING.
//  - R5 measured 3.0us/step, all pipes <5% busy: the publish->visible->detect
//    L3 round trip (~1500cy + poll quantization) dominates each step.
//  - Fix: each block serves TWO independent batch-groups (A=2p, B=2p+1) with
//    the same LDS W slice (W is batch-invariant). Alternating phases
//    A(t),B(t),A(t+1),... fill group A's exchange latency with group B's
//    compute. First poll then succeeds ~always; period ~= 2 x compute phase.
//  - 64 blocks = 4 pairs x 16 col-slices. Everything else from R5 unchanged:
//    * tag-in-data: relu(h)>=0 -> sign bits carry gen tag ((t>>1)&1), 2-slot
//      ring, agent-scope relaxed atomics (L3-coherent), no barriers/flags.
//    * cooperative h staging: 256 thr x 128B -> LDS htile, batched retry
//      with s_sleep backoff.
//    * W chunks 0..29 in LDS (XOR-swizzled granules), 30,31 + x-chunks in
//      per-lane registers.
// ---------------------------------------------------------------------------

typedef _Float16 half8 __attribute__((ext_vector_type(8)));
typedef float    f32x4 __attribute__((ext_vector_type(4)));
typedef unsigned short ushort8 __attribute__((ext_vector_type(8)));
typedef unsigned long long u64;

#define SIGMA_F 0.05f

constexpr int T_  = 256;
constexpr int B_  = 128;
constexpr int NH  = 1024;
constexpr int NIN = 128;
constexpr int GN  = 16;           // column slices (64 cols each)
constexpr int NPAIR = 4;          // group pairs; groups = 8 (16 rows each)

constexpr u64 TMASK = 0x8000800080008000ULL;
constexpr u64 DMASK = 0x7FFF7FFF7FFF7FFFULL;

// workspace layout (bytes)
constexpr size_t OFF_XT  = 0;                            // fp16 [T][B][NIN] 8.39MB
constexpr size_t OFF_NB  = (size_t)T_*B_*NIN*2;          // f32  [T][NH]     1.05MB
constexpr size_t OFF_WO  = OFF_NB + (size_t)T_*NH*4;     // fp16 [NIN][NH]   0.26MB
constexpr size_t OFF_HB  = OFF_WO + (size_t)NIN*NH*2;    // u32 [2][B][512]  0.52MB

__device__ __forceinline__ unsigned short f16bits(float v) {
    return __half_as_ushort(__float2half(v));
}
__device__ __forceinline__ u64 ald(const u64* p) {
    return __hip_atomic_load(p, __ATOMIC_RELAXED, __HIP_MEMORY_SCOPE_AGENT);
}
__device__ __forceinline__ void ast(unsigned int* p, unsigned int v) {
    __hip_atomic_store(p, v, __ATOMIC_RELAXED, __HIP_MEMORY_SCOPE_AGENT);
}

// ---------------------------------------------------------------------------
__global__ void setup_kernel(const float* __restrict__ X,
                             const float* __restrict__ hidden,
                             const float* __restrict__ b_hh,
                             const float* __restrict__ W_out,
                             const float* __restrict__ alpha_w,
                             const float* __restrict__ noise,
                             unsigned short* __restrict__ Xt,
                             float* __restrict__ NB,
                             unsigned short* __restrict__ Wo,
                             unsigned int* __restrict__ Hb0,
                             unsigned int* __restrict__ Hb1)
{
    int idx = blockIdx.x * 256 + threadIdx.x;
    // X [B][T][NIN] -> Xt [T][B][NIN] fp16
    if (idx < B_ * T_ * NIN) {
        int d = idx & 127, rest = idx >> 7;
        int brow = rest & 127, t = rest >> 7;
        Xt[idx] = f16bits(X[((size_t)brow * T_ + t) * NIN + d]);
    }
    if (idx < T_ * NH) {
        int c = idx & (NH - 1);
        NB[idx] = b_hh[c] + noise[idx] * (sqrtf(2.0f / alpha_w[c]) * SIGMA_F);
    }
    if (idx < NIN * NH) Wo[idx] = f16bits(W_out[idx]);
    if (idx < B_ * NH / 2) {
        // slot0 = initial h with gen-0 tag (0); slot1 = poison (tag 1)
        unsigned int lo = f16bits(hidden[idx * 2]);
        unsigned int hi = f16bits(hidden[idx * 2 + 1]);
        Hb0[idx] = (lo | (hi << 16)) & 0x7FFF7FFFu;
        Hb1[idx] = 0x80008000u;
    }
}

// ---------------------------------------------------------------------------
// Dual-domain persistent RNN: 64 blocks x 256 threads (4 waves, 1 block/CU).
// Block (p = bx>>4 group-pair, n = bx&15 col-slice). Wave owns 16 cols.
__global__ __launch_bounds__(256, 1) void rnn_step_kernel(
    const float* __restrict__ W_hh, const float* __restrict__ W_in,
    const unsigned short* __restrict__ Xt, const float* __restrict__ NB,
    unsigned int* __restrict__ Hb0, unsigned int* __restrict__ Hb1,
    float* __restrict__ hidden_list, float* __restrict__ h_final)
{
    __shared__ unsigned short wtile[64 * 960];    // 122,880 B (chunks 0..29)
    __shared__ unsigned short htile[16 * 1024];   //  32,768 B (one group's h)

    const int tid = threadIdx.x;
    const int n = blockIdx.x & 15;   // column slice
    const int p = blockIdx.x >> 4;   // group pair -> groups 2p, 2p+1

    const int wave = tid >> 6, lane = tid & 63;
    const int l15 = lane & 15, lk = lane >> 4;
    const int colW = wave * 16 + l15;       // local W row / output col
    const int gcol = n * 64 + colW;         // global hidden col

    // ---- stage W chunks 0..29 into LDS (swizzled granules) ----
    for (int g = tid; g < 64 * 120; g += 256) {
        int row = g / 120, G = g - row * 120;
        const float* s = W_hh + (size_t)(n * 64 + row) * NH + G * 8;
        half8 h;
        #pragma unroll
        for (int j = 0; j < 8; ++j) h[j] = (_Float16)s[j];
        *(half8*)&wtile[row * 960 + ((G ^ (row & 7)) << 3)] = h;
    }

    // ---- per-lane register B-fragments: W_hh chunks 30,31 + W_in 4 chunks ----
    auto cvt8 = [](const float* s) {
        half8 h;
        #pragma unroll
        for (int j = 0; j < 8; ++j) h[j] = (_Float16)s[j];
        return h;
    };
    half8 bh30 = cvt8(W_hh + (size_t)gcol * NH + 960 + lk * 8);
    half8 bh31 = cvt8(W_hh + (size_t)gcol * NH + 992 + lk * 8);
    half8 bx[4];
    #pragma unroll
    for (int kx = 0; kx < 4; ++kx)
        bx[kx] = cvt8(W_in + (size_t)gcol * NIN + kx * 32 + lk * 8);
    __syncthreads();

    // h staging role: thread -> (row, part); 8 granules G = j*16+part
    const int hrow = tid >> 4;       // 0..15
    const int part = tid & 15;

    auto xpart = [&](int grp, int t) -> f32x4 {
        f32x4 a = {0.f, 0.f, 0.f, 0.f};
        const int rowA = grp * 16 + l15;
        const ushort8* xp = (const ushort8*)(Xt + ((size_t)t * B_ + rowA) * NIN) + lk;
        #pragma unroll
        for (int kx = 0; kx < 4; ++kx) {
            half8 av = __builtin_bit_cast(half8, xp[kx * 4]);
            a = __builtin_amdgcn_mfma_f32_16x16x32_f16(av, bx[kx], a, 0, 0, 0);
        }
        return a;
    };

    // one group-phase: spin -> stage -> MFMA -> relu -> publish -> outputs
    auto phase = [&](int grp, int t, f32x4& accx) {
        // phase 1: cooperative tagged load of group h (128B/thread)
        const u64* hp = (const u64*)((t & 1) ? Hb1 : Hb0)
                        + (size_t)(grp * 16 + hrow) * 256 + part * 2;
        const u64 expq = ((t >> 1) & 1) ? TMASK : 0ULL;
        u64 q[16];
        for (;;) {
            #pragma unroll
            for (int j = 0; j < 8; ++j) {
                q[2*j]   = ald(hp + j * 32);
                q[2*j+1] = ald(hp + j * 32 + 1);
            }
            u64 red = 0;
            #pragma unroll
            for (int i = 0; i < 16; ++i) red |= q[i] ^ expq;
            if ((red & TMASK) == 0ULL) break;
            __builtin_amdgcn_s_sleep(2);   // backoff only on miss
        }

        __syncthreads();   // prior-phase htile reads complete (WAR)

        // strip tags, stage to LDS (swizzled granules)
        #pragma unroll
        for (int j = 0; j < 8; ++j) {
            union { u64 w[2]; half8 h; } u;
            u.w[0] = q[2*j]   & DMASK;
            u.w[1] = q[2*j+1] & DMASK;
            int G = j * 16 + part;
            *(half8*)&htile[hrow * 1024 + ((G ^ (hrow & 7)) << 3)] = u.h;
        }

        __syncthreads();   // htile ready

        // phase 2: 36 MFMAs (30 LDS-B + 2 reg-B; 4 x-chunks already in accx)
        f32x4 acc = accx;
        #pragma unroll
        for (int ki = 0; ki < 30; ++ki) {
            int G = 4 * ki + lk;
            half8 av = *(const half8*)&htile[l15 * 1024 + ((G ^ (l15 & 7)) << 3)];
            half8 bv = *(const half8*)&wtile[colW * 960 + ((G ^ (colW & 7)) << 3)];
            acc = __builtin_amdgcn_mfma_f32_16x16x32_f16(av, bv, acc, 0, 0, 0);
        }
        {
            int G = 120 + lk;
            half8 av = *(const half8*)&htile[l15 * 1024 + ((G ^ (l15 & 7)) << 3)];
            acc = __builtin_amdgcn_mfma_f32_16x16x32_f16(av, bh30, acc, 0, 0, 0);
            G = 124 + lk;
            av = *(const half8*)&htile[l15 * 1024 + ((G ^ (l15 & 7)) << 3)];
            acc = __builtin_amdgcn_mfma_f32_16x16x32_f16(av, bh31, acc, 0, 0, 0);
        }

        // bias+noise, relu
        const float nb = NB[t * NH + gcol];
        float hv[4];
        #pragma unroll
        for (int r = 0; r < 4; ++r) {
            float v = acc[r] + nb;
            hv[r] = v > 0.f ? v : 0.f;
        }

        // publish h_{t+1} FIRST (tag carried in-word, fire-and-forget)
        if (t < T_ - 1) {
            unsigned int* hn = (t & 1) ? Hb0 : Hb1;
            const unsigned int tagb = (((t + 1) >> 1) & 1) ? 0x80008000u : 0u;
            #pragma unroll
            for (int r = 0; r < 4; ++r) {
                float other = __shfl_xor(hv[r], 1);
                if (!(lane & 1)) {
                    unsigned int val = (unsigned int)f16bits(hv[r]) |
                                       ((unsigned int)f16bits(other) << 16) | tagb;
                    int brow = grp * 16 + lk * 4 + r;
                    ast(&hn[(size_t)brow * 512 + (gcol >> 1)], val);
                }
            }
        }

        // off-critical-path: fp32 outputs, next x-part
        #pragma unroll
        for (int r = 0; r < 4; ++r) {
            int brow = grp * 16 + lk * 4 + r;
            hidden_list[((size_t)brow * T_ + t) * NH + gcol] = hv[r];
        }
        if (t == T_ - 1) {
            #pragma unroll
            for (int r = 0; r < 4; ++r) {
                int brow = grp * 16 + lk * 4 + r;
                h_final[(size_t)brow * NH + gcol] = hv[r];
            }
        } else {
            accx = xpart(grp, t + 1);
        }
    };

    f32x4 accxA = xpart(2 * p, 0);
    f32x4 accxB = xpart(2 * p + 1, 0);

    for (int t = 0; t < T_; ++t) {
        phase(2 * p,     t, accxA);   // group A: poll issued ~1 phase after
        phase(2 * p + 1, t, accxB);   // peers published -> first-round hit
    }
}

// ---------------------------------------------------------------------------
// Readout: Y[32768,128] = HL[32768,1024](f32->f16) @ Wo^T(f16), fp32 out.
__global__ __launch_bounds__(256, 4) void ygemm_kernel(
    const float* __restrict__ HL, const unsigned short* __restrict__ Wo,
    float* __restrict__ Y)
{
    const int tid = threadIdx.x;
    const int wave = tid >> 6, lane = tid & 63;
    const int l15 = lane & 15, lk = lane >> 4;
    const size_t rowbase = (size_t)blockIdx.x * 64;

    f32x4 acc[4][2] = {};

    #pragma unroll 2
    for (int ki = 0; ki < 32; ++ki) {
        const int k0 = ki * 32 + lk * 8;
        half8 bfr[2];
        #pragma unroll
        for (int nt = 0; nt < 2; ++nt) {
            int ncol = (wave * 2 + nt) * 16 + l15;
            ushort8 braw = *(const ushort8*)(Wo + ncol * NH + k0);
            bfr[nt] = __builtin_bit_cast(half8, braw);
        }
        #pragma unroll
        for (int mt = 0; mt < 4; ++mt) {
            size_t row = rowbase + mt * 16 + l15;
            const float4* ap = (const float4*)(HL + row * NH + k0);
            float4 a0 = ap[0];
            float4 a1 = ap[1];
            half8 a = { (_Float16)a0.x, (_Float16)a0.y, (_Float16)a0.z, (_Float16)a0.w,
                        (_Float16)a1.x, (_Float16)a1.y, (_Float16)a1.z, (_Float16)a1.w };
            #pragma unroll
            for (int nt = 0; nt < 2; ++nt)
                acc[mt][nt] = __builtin_amdgcn_mfma_f32_16x16x32_f16(a, bfr[nt], acc[mt][nt], 0, 0, 0);
        }
    }

    #pragma unroll
    for (int mt = 0; mt < 4; ++mt) {
        #pragma unroll
        for (int nt = 0; nt < 2; ++nt) {
            int ncol = (wave * 2 + nt) * 16 + l15;
            #pragma unroll
            for (int r = 0; r < 4; ++r) {
                size_t row = rowbase + mt * 16 + lk * 4 + r;
                Y[row * NIN + ncol] = acc[mt][nt][r];
            }
        }
    }
}

// ---------------------------------------------------------------------------
extern "C" void kernel_launch(void* const* d_in, const int* in_sizes, int n_in,
                              void* d_out, int out_size, void* d_ws, size_t ws_size,
                              hipStream_t stream)
{
    const float* X      = (const float*)d_in[0];
    const float* hidden = (const float*)d_in[1];
    const float* W_in   = (const float*)d_in[2];
    const float* W_hh   = (const float*)d_in[3];
    const float* b_hh   = (const float*)d_in[4];
    const float* W_out  = (const float*)d_in[5];
    const float* alpha  = (const float*)d_in[6];
    const float* noise  = (const float*)d_in[7];

    char* ws = (char*)d_ws;   // ~10.2 MB
    unsigned short* Xt = (unsigned short*)(ws + OFF_XT);
    float*          NB = (float*)(ws + OFF_NB);
    unsigned short* Wo = (unsigned short*)(ws + OFF_WO);
    unsigned int*  Hb0 = (unsigned int*)(ws + OFF_HB);
    unsigned int*  Hb1 = Hb0 + (size_t)B_ * NH / 2;

    float* hidden_list = (float*)d_out;                                  // [128,256,1024]
    float* output_list = hidden_list + (size_t)B_ * T_ * NH;             // [128,256,128]
    float* h_final     = output_list + (size_t)B_ * T_ * NIN;            // [128,1024]

    setup_kernel<<<(B_ * T_ * NIN + 255) / 256, 256, 0, stream>>>(
        X, hidden, b_hh, W_out, alpha, noise, Xt, NB, Wo, Hb0, Hb1);

    rnn_step_kernel<<<NPAIR * GN, 256, 0, stream>>>(
        W_hh, W_in, Xt, NB, Hb0, Hb1, hidden_list, h_final);

    ygemm_kernel<<<(B_ * T_) / 64, 256, 0, stream>>>(
        hidden_list, Wo, output_list);
}

// Round 7
// 1240.661 us; speedup vs baseline: 1.3034x; 1.3034x over previous
//
#include <hip/hip_runtime.h>
#include <hip/hip_fp16.h>
#include <math.h>

// ---------------------------------------------------------------------------
// RNN: h_{t+1} = relu(x_t @ W_in^T + h_t @ W_hh^T + b_hh + noise_t*scale)
// outputs: hidden_list [128,256,1024] f32, output_list [128,256,128] f32,
//          h_final [128,1024] f32 (concatenated flat in d_out)
//
// R7 = R5 skeleton (proven 777us) + SEGMENT-PIPELINED exchange.
//  - R6 lesson: multiplexing 2 batch-groups through one block serialized the
//    waits (per-CU utilization identical to R5; step time exactly 2x) -> the
//    per-phase wait is not hidden by adding a second serial phase. Reverted.
//  - R5 wait (~60% of step) = visibility + producer skew + poll quantization
//    (full-32KB reload rounds). Fix: h(t) arrives in 16 independent 64-col
//    segments from 16 producer blocks. Process in 4 super-segments (256 cols
//    = 8 k-chunks): spin only on segment s, stage, MFMA s WHILE segment s+1
//    loads fly (issued pre-sync, validated post-MFMA). Early producers are
//    consumed during stragglers' flight; retry rounds shrink 32KB -> 8KB.
//  - Tail: seg-0 loads of t+1 issued right after publish, overlapped with
//    fp32 output stores + x-part MFMAs, validated last.
//  - Everything else per R5: tag-in-data (relu(h)>=0 -> sign bits carry gen
//    tag (t>>1)&1, 2-slot ring, agent-relaxed L3-coherent ops), cooperative
//    staging, W chunks 0..29 LDS (XOR-swizzled granules) + 30,31 & x in regs.
// ---------------------------------------------------------------------------

typedef _Float16 half8 __attribute__((ext_vector_type(8)));
typedef float    f32x4 __attribute__((ext_vector_type(4)));
typedef unsigned short ushort8 __attribute__((ext_vector_type(8)));
typedef unsigned long long u64;

#define SIGMA_F 0.05f

constexpr int T_  = 256;
constexpr int B_  = 128;
constexpr int NH  = 1024;
constexpr int NIN = 128;
constexpr int GM  = 8;            // batch groups (16 rows each)
constexpr int GN  = 16;           // column slices (64 cols each)
constexpr int MB  = 16;

constexpr u64 TMASK = 0x8000800080008000ULL;
constexpr u64 DMASK = 0x7FFF7FFF7FFF7FFFULL;

// workspace layout (bytes)
constexpr size_t OFF_XT  = 0;                            // fp16 [T][B][NIN] 8.39MB
constexpr size_t OFF_NB  = (size_t)T_*B_*NIN*2;          // f32  [T][NH]     1.05MB
constexpr size_t OFF_WO  = OFF_NB + (size_t)T_*NH*4;     // fp16 [NIN][NH]   0.26MB
constexpr size_t OFF_HB  = OFF_WO + (size_t)NIN*NH*2;    // u32 [2][B][512]  0.52MB

__device__ __forceinline__ unsigned short f16bits(float v) {
    return __half_as_ushort(__float2half(v));
}
__device__ __forceinline__ u64 ald(const u64* p) {
    return __hip_atomic_load(p, __ATOMIC_RELAXED, __HIP_MEMORY_SCOPE_AGENT);
}
__device__ __forceinline__ void ast(unsigned int* p, unsigned int v) {
    __hip_atomic_store(p, v, __ATOMIC_RELAXED, __HIP_MEMORY_SCOPE_AGENT);
}

// ---------------------------------------------------------------------------
__global__ void setup_kernel(const float* __restrict__ X,
                             const float* __restrict__ hidden,
                             const float* __restrict__ b_hh,
                             const float* __restrict__ W_out,
                             const float* __restrict__ alpha_w,
                             const float* __restrict__ noise,
                             unsigned short* __restrict__ Xt,
                             float* __restrict__ NB,
                             unsigned short* __restrict__ Wo,
                             unsigned int* __restrict__ Hb0,
                             unsigned int* __restrict__ Hb1)
{
    int idx = blockIdx.x * 256 + threadIdx.x;
    // X [B][T][NIN] -> Xt [T][B][NIN] fp16
    if (idx < B_ * T_ * NIN) {
        int d = idx & 127, rest = idx >> 7;
        int brow = rest & 127, t = rest >> 7;
        Xt[idx] = f16bits(X[((size_t)brow * T_ + t) * NIN + d]);
    }
    if (idx < T_ * NH) {
        int c = idx & (NH - 1);
        NB[idx] = b_hh[c] + noise[idx] * (sqrtf(2.0f / alpha_w[c]) * SIGMA_F);
    }
    if (idx < NIN * NH) Wo[idx] = f16bits(W_out[idx]);
    if (idx < B_ * NH / 2) {
        // slot0 = initial h with gen-0 tag (0); slot1 = poison (tag 1)
        unsigned int lo = f16bits(hidden[idx * 2]);
        unsigned int hi = f16bits(hidden[idx * 2 + 1]);
        Hb0[idx] = (lo | (hi << 16)) & 0x7FFF7FFFu;
        Hb1[idx] = 0x80008000u;
    }
}

// ---------------------------------------------------------------------------
// Barrier-free persistent RNN: 128 blocks x 256 threads (4 waves, 1 block/CU).
__global__ __launch_bounds__(256, 1) void rnn_step_kernel(
    const float* __restrict__ W_hh, const float* __restrict__ W_in,
    const unsigned short* __restrict__ Xt, const float* __restrict__ NB,
    unsigned int* __restrict__ Hb0, unsigned int* __restrict__ Hb1,
    float* __restrict__ hidden_list, float* __restrict__ h_final)
{
    __shared__ unsigned short wtile[64 * 960];    // 122,880 B (chunks 0..29)
    __shared__ unsigned short htile[16 * 1024];   //  32,768 B (full h tile)

    const int tid = threadIdx.x;
    const int m = blockIdx.x / GN;   // batch group
    const int n = blockIdx.x % GN;   // column slice

    // ---- stage W chunks 0..29 into LDS (swizzled granules) ----
    for (int g = tid; g < 64 * 120; g += 256) {
        int row = g / 120, G = g - row * 120;
        const float* s = W_hh + (size_t)(n * 64 + row) * NH + G * 8;
        half8 h;
        #pragma unroll
        for (int j = 0; j < 8; ++j) h[j] = (_Float16)s[j];
        *(half8*)&wtile[row * 960 + ((G ^ (row & 7)) << 3)] = h;
    }

    const int wave = tid >> 6, lane = tid & 63;
    const int l15 = lane & 15, lk = lane >> 4;
    const int colW = wave * 16 + l15;       // local W row / output col
    const int gcol = n * 64 + colW;         // global hidden col

    // ---- per-lane register B-fragments: W_hh chunks 30,31 + W_in 4 chunks ----
    auto cvt8 = [](const float* s) {
        half8 h;
        #pragma unroll
        for (int j = 0; j < 8; ++j) h[j] = (_Float16)s[j];
        return h;
    };
    half8 bh30 = cvt8(W_hh + (size_t)gcol * NH + 960 + lk * 8);
    half8 bh31 = cvt8(W_hh + (size_t)gcol * NH + 992 + lk * 8);
    half8 bx[4];
    #pragma unroll
    for (int kx = 0; kx < 4; ++kx)
        bx[kx] = cvt8(W_in + (size_t)gcol * NIN + kx * 32 + lk * 8);
    __syncthreads();

    // h staging role: thread (hrow, part); per super-segment s the thread
    // owns u64s [64s + 4*part .. +3] of row hrow (32B, coalesced).
    const int hrow = tid >> 4;       // 0..15
    const int part = tid & 15;

    auto xpart = [&](int t) -> f32x4 {
        f32x4 a = {0.f, 0.f, 0.f, 0.f};
        const int rowA = m * MB + l15;
        const ushort8* xp = (const ushort8*)(Xt + ((size_t)t * B_ + rowA) * NIN) + lk;
        #pragma unroll
        for (int kx = 0; kx < 4; ++kx) {
            half8 av = __builtin_bit_cast(half8, xp[kx * 4]);
            a = __builtin_amdgcn_mfma_f32_16x16x32_f16(av, bx[kx], a, 0, 0, 0);
        }
        return a;
    };

    // stage 4 validated u64 (strip tags) into htile region s
    auto stage_seg = [&](int s, const u64 q[4]) {
        union { u64 w[2]; half8 h; } u0, u1;
        u0.w[0] = q[0] & DMASK; u0.w[1] = q[1] & DMASK;
        u1.w[0] = q[2] & DMASK; u1.w[1] = q[3] & DMASK;
        int G0 = 32 * s + 2 * part;
        *(half8*)&htile[hrow * 1024 + ((G0 ^ (hrow & 7)) << 3)] = u0.h;
        *(half8*)&htile[hrow * 1024 + (((G0 + 1) ^ (hrow & 7)) << 3)] = u1.h;
    };

    f32x4 accx = xpart(0);

    // prologue: spin-load segment 0 of t=0 (expq = 0)
    u64 qa[4];
    {
        const u64* hp = (const u64*)Hb0 + (size_t)(m * MB + hrow) * 256 + 4 * part;
        for (;;) {
            qa[0] = ald(hp); qa[1] = ald(hp + 1);
            qa[2] = ald(hp + 2); qa[3] = ald(hp + 3);
            if (!((qa[0] | qa[1] | qa[2] | qa[3]) & TMASK)) break;
            __builtin_amdgcn_s_sleep(1);
        }
    }

    for (int t = 0; t < T_; ++t) {
        const u64* hrowp = (const u64*)((t & 1) ? Hb1 : Hb0)
                           + (size_t)(m * MB + hrow) * 256 + 4 * part;
        const u64 expq = ((t >> 1) & 1) ? TMASK : 0ULL;
        f32x4 acc = accx;
        u64 qb[4];

        #pragma unroll
        for (int s = 0; s < 4; ++s) {
            stage_seg(s, qa);
            if (s < 3) {                      // issue next segment pre-sync
                const u64* p = hrowp + 64 * (s + 1);
                qb[0] = ald(p);     qb[1] = ald(p + 1);
                qb[2] = ald(p + 2); qb[3] = ald(p + 3);
            }
            __syncthreads();                  // region s staged & visible

            if (s < 3) {
                #pragma unroll
                for (int j = 0; j < 8; ++j) {
                    int ki = 8 * s + j;
                    int G = 4 * ki + lk;
                    half8 av = *(const half8*)&htile[l15 * 1024 + ((G ^ (l15 & 7)) << 3)];
                    half8 bv = *(const half8*)&wtile[colW * 960 + ((G ^ (colW & 7)) << 3)];
                    acc = __builtin_amdgcn_mfma_f32_16x16x32_f16(av, bv, acc, 0, 0, 0);
                }
                // validate next segment (loads overlapped the MFMAs above)
                const u64* p = hrowp + 64 * (s + 1);
                for (;;) {
                    u64 red = (qb[0] ^ expq) | (qb[1] ^ expq) |
                              (qb[2] ^ expq) | (qb[3] ^ expq);
                    if (!(red & TMASK)) break;
                    __builtin_amdgcn_s_sleep(1);
                    qb[0] = ald(p);     qb[1] = ald(p + 1);
                    qb[2] = ald(p + 2); qb[3] = ald(p + 3);
                }
                qa[0] = qb[0]; qa[1] = qb[1]; qa[2] = qb[2]; qa[3] = qb[3];
            } else {
                #pragma unroll
                for (int j = 0; j < 6; ++j) {
                    int ki = 24 + j;
                    int G = 4 * ki + lk;
                    half8 av = *(const half8*)&htile[l15 * 1024 + ((G ^ (l15 & 7)) << 3)];
                    half8 bv = *(const half8*)&wtile[colW * 960 + ((G ^ (colW & 7)) << 3)];
                    acc = __builtin_amdgcn_mfma_f32_16x16x32_f16(av, bv, acc, 0, 0, 0);
                }
                int G = 120 + lk;
                half8 av = *(const half8*)&htile[l15 * 1024 + ((G ^ (l15 & 7)) << 3)];
                acc = __builtin_amdgcn_mfma_f32_16x16x32_f16(av, bh30, acc, 0, 0, 0);
                G = 124 + lk;
                av = *(const half8*)&htile[l15 * 1024 + ((G ^ (l15 & 7)) << 3)];
                acc = __builtin_amdgcn_mfma_f32_16x16x32_f16(av, bh31, acc, 0, 0, 0);
            }
        }

        // ---- bias+noise, relu ----
        const float nb = NB[t * NH + gcol];
        float hv[4];
        #pragma unroll
        for (int r = 0; r < 4; ++r) {
            float v = acc[r] + nb;
            hv[r] = v > 0.f ? v : 0.f;
        }

        if (t < T_ - 1) {
            // publish h_{t+1} FIRST (tag in-word, fire-and-forget)
            unsigned int* hn = (t & 1) ? Hb0 : Hb1;
            const unsigned int tagb = (((t + 1) >> 1) & 1) ? 0x80008000u : 0u;
            #pragma unroll
            for (int r = 0; r < 4; ++r) {
                float other = __shfl_xor(hv[r], 1);
                if (!(lane & 1)) {
                    unsigned int val = (unsigned int)f16bits(hv[r]) |
                                       ((unsigned int)f16bits(other) << 16) | tagb;
                    int brow = m * MB + lk * 4 + r;
                    ast(&hn[(size_t)brow * 512 + (gcol >> 1)], val);
                }
            }
            // issue seg-0 loads of t+1 (overlap with stores + x-part below)
            const u64* hp2 = (const u64*)(((t + 1) & 1) ? Hb1 : Hb0)
                             + (size_t)(m * MB + hrow) * 256 + 4 * part;
            qa[0] = ald(hp2);     qa[1] = ald(hp2 + 1);
            qa[2] = ald(hp2 + 2); qa[3] = ald(hp2 + 3);

            #pragma unroll
            for (int r = 0; r < 4; ++r) {
                int brow = m * MB + lk * 4 + r;
                hidden_list[((size_t)brow * T_ + t) * NH + gcol] = hv[r];
            }
            accx = xpart(t + 1);

            // validate seg 0 of t+1
            const u64 e2 = (((t + 1) >> 1) & 1) ? TMASK : 0ULL;
            for (;;) {
                u64 red = (qa[0] ^ e2) | (qa[1] ^ e2) |
                          (qa[2] ^ e2) | (qa[3] ^ e2);
                if (!(red & TMASK)) break;
                __builtin_amdgcn_s_sleep(1);
                qa[0] = ald(hp2);     qa[1] = ald(hp2 + 1);
                qa[2] = ald(hp2 + 2); qa[3] = ald(hp2 + 3);
            }
        } else {
            #pragma unroll
            for (int r = 0; r < 4; ++r) {
                int brow = m * MB + lk * 4 + r;
                hidden_list[((size_t)brow * T_ + t) * NH + gcol] = hv[r];
                h_final[(size_t)brow * NH + gcol] = hv[r];
            }
        }
    }
}

// ---------------------------------------------------------------------------
// Readout: Y[32768,128] = HL[32768,1024](f32->f16) @ Wo^T(f16), fp32 out.
__global__ __launch_bounds__(256, 4) void ygemm_kernel(
    const float* __restrict__ HL, const unsigned short* __restrict__ Wo,
    float* __restrict__ Y)
{
    const int tid = threadIdx.x;
    const int wave = tid >> 6, lane = tid & 63;
    const int l15 = lane & 15, lk = lane >> 4;
    const size_t rowbase = (size_t)blockIdx.x * 64;

    f32x4 acc[4][2] = {};

    #pragma unroll 2
    for (int ki = 0; ki < 32; ++ki) {
        const int k0 = ki * 32 + lk * 8;
        half8 bfr[2];
        #pragma unroll
        for (int nt = 0; nt < 2; ++nt) {
            int ncol = (wave * 2 + nt) * 16 + l15;
            ushort8 braw = *(const ushort8*)(Wo + ncol * NH + k0);
            bfr[nt] = __builtin_bit_cast(half8, braw);
        }
        #pragma unroll
        for (int mt = 0; mt < 4; ++mt) {
            size_t row = rowbase + mt * 16 + l15;
            const float4* ap = (const float4*)(HL + row * NH + k0);
            float4 a0 = ap[0];
            float4 a1 = ap[1];
            half8 a = { (_Float16)a0.x, (_Float16)a0.y, (_Float16)a0.z, (_Float16)a0.w,
                        (_Float16)a1.x, (_Float16)a1.y, (_Float16)a1.z, (_Float16)a1.w };
            #pragma unroll
            for (int nt = 0; nt < 2; ++nt)
                acc[mt][nt] = __builtin_amdgcn_mfma_f32_16x16x32_f16(a, bfr[nt], acc[mt][nt], 0, 0, 0);
        }
    }

    #pragma unroll
    for (int mt = 0; mt < 4; ++mt) {
        #pragma unroll
        for (int nt = 0; nt < 2; ++nt) {
            int ncol = (wave * 2 + nt) * 16 + l15;
            #pragma unroll
            for (int r = 0; r < 4; ++r) {
                size_t row = rowbase + mt * 16 + lk * 4 + r;
                Y[row * NIN + ncol] = acc[mt][nt][r];
            }
        }
    }
}

// ---------------------------------------------------------------------------
extern "C" void kernel_launch(void* const* d_in, const int* in_sizes, int n_in,
                              void* d_out, int out_size, void* d_ws, size_t ws_size,
                              hipStream_t stream)
{
    const float* X      = (const float*)d_in[0];
    const float* hidden = (const float*)d_in[1];
    const float* W_in   = (const float*)d_in[2];
    const float* W_hh   = (const float*)d_in[3];
    const float* b_hh   = (const float*)d_in[4];
    const float* W_out  = (const float*)d_in[5];
    const float* alpha  = (const float*)d_in[6];
    const float* noise  = (const float*)d_in[7];

    char* ws = (char*)d_ws;   // ~10.2 MB
    unsigned short* Xt = (unsigned short*)(ws + OFF_XT);
    float*          NB = (float*)(ws + OFF_NB);
    unsigned short* Wo = (unsigned short*)(ws + OFF_WO);
    unsigned int*  Hb0 = (unsigned int*)(ws + OFF_HB);
    unsigned int*  Hb1 = Hb0 + (size_t)B_ * NH / 2;

    float* hidden_list = (float*)d_out;                                  // [128,256,1024]
    float* output_list = hidden_list + (size_t)B_ * T_ * NH;             // [128,256,128]
    float* h_final     = output_list + (size_t)B_ * T_ * NIN;            // [128,1024]

    setup_kernel<<<(B_ * T_ * NIN + 255) / 256, 256, 0, stream>>>(
        X, hidden, b_hh, W_out, alpha, noise, Xt, NB, Wo, Hb0, Hb1);

    rnn_step_kernel<<<GM * GN, 256, 0, stream>>>(
        W_hh, W_in, Xt, NB, Hb0, Hb1, hidden_list, h_final);

    ygemm_kernel<<<(B_ * T_) / 64, 256, 0, stream>>>(
        hidden_list, Wo, output_list);
}

// Round 9
// 823.187 us; speedup vs baseline: 1.9644x; 1.5071x over previous
//
#include <hip/hip_runtime.h>
#include <hip/hip_fp16.h>
#include <math.h>

// ---------------------------------------------------------------------------
// RNN: h_{t+1} = relu(x_t @ W_in^T + h_t @ W_hh^T + b_hh + noise_t*scale)
// outputs: hidden_list [128,256,1024] f32, output_list [128,256,128] f32,
//          h_final [128,1024] f32 (concatenated flat in d_out)
//
// R9 = R5 (proven 777us) + XCD-striped roles + ESCALATING spin (sc0 fast
// path -> agent-scope fallback). R8 post-mortem: claim-based XCD pinning can
// deadlock under skewed (undefined) dispatch, and sc0 loads may not bypass
// L1 -> eternal stale spin. R9 is correct under ALL semantic variants:
//  - Roles fixed by blockIdx: m = bx&7, n = bx>>3. Under default round-robin
//    blockIdx->XCD mapping each group's 16 blocks share one XCD (locality
//    HEURISTIC only; correctness independent of mapping).
//  - Spin: 3 rounds of sc0 dwordx4 loads (if sc0 = L1-bypass, these are
//    L2-served ~300cy and see same-XCD sc1 stores which write through L2;
//    if sc0 is L1-sticky the rounds are ~free L1 hits), then escalate to
//    __hip_atomic_load(AGENT) (L3-coherent, R5-proven) + s_sleep backoff.
//    Producers publish with agent-scope stores (R5-proven visibility).
//    => progress guaranteed by the fallback, fast when locality holds.
//  - Everything else identical to R5: tag-in-data (relu(h)>=0 frees fp16
//    sign bits; gen tag (t>>1)&1; 2-slot ring), cooperative LDS h-staging
//    (2 barriers), W chunks 0..29 in XOR-swizzled LDS, 30,31 + x in regs.
// ---------------------------------------------------------------------------

typedef _Float16 half8 __attribute__((ext_vector_type(8)));
typedef float    f32x4 __attribute__((ext_vector_type(4)));
typedef unsigned short ushort8 __attribute__((ext_vector_type(8)));
typedef unsigned int u32x4 __attribute__((ext_vector_type(4)));
typedef unsigned long long u64;

#define SIGMA_F 0.05f

constexpr int T_  = 256;
constexpr int B_  = 128;
constexpr int NH  = 1024;
constexpr int NIN = 128;
constexpr int MB  = 16;           // batch rows per group

// workspace layout (bytes)
constexpr size_t OFF_XT  = 0;                            // fp16 [T][B][NIN] 8.39MB
constexpr size_t OFF_NB  = (size_t)T_*B_*NIN*2;          // f32  [T][NH]     1.05MB
constexpr size_t OFF_WO  = OFF_NB + (size_t)T_*NH*4;     // fp16 [NIN][NH]   0.26MB
constexpr size_t OFF_HB  = OFF_WO + (size_t)NIN*NH*2;    // u32 [2][B][512]  0.52MB

__device__ __forceinline__ unsigned short f16bits(float v) {
    return __half_as_ushort(__float2half(v));
}
__device__ __forceinline__ u64 ald(const u64* p) {
    return __hip_atomic_load(p, __ATOMIC_RELAXED, __HIP_MEMORY_SCOPE_AGENT);
}
__device__ __forceinline__ void ast(unsigned int* p, unsigned int v) {
    __hip_atomic_store(p, v, __ATOMIC_RELAXED, __HIP_MEMORY_SCOPE_AGENT);
}

// 8x dwordx4 at 256B stride, sc0 (L1-bypass on the favorable semantics;
// harmless cheap L1 hits otherwise). One waitcnt for the batch.
__device__ __forceinline__ void ld8_sc0(u32x4 r[8], const u64* p) {
    asm volatile(
        "global_load_dwordx4 %0, %8, off sc0\n\t"
        "global_load_dwordx4 %1, %8, off offset:256 sc0\n\t"
        "global_load_dwordx4 %2, %8, off offset:512 sc0\n\t"
        "global_load_dwordx4 %3, %8, off offset:768 sc0\n\t"
        "global_load_dwordx4 %4, %8, off offset:1024 sc0\n\t"
        "global_load_dwordx4 %5, %8, off offset:1280 sc0\n\t"
        "global_load_dwordx4 %6, %8, off offset:1536 sc0\n\t"
        "global_load_dwordx4 %7, %8, off offset:1792 sc0\n\t"
        "s_waitcnt vmcnt(0)"
        : "=&v"(r[0]), "=&v"(r[1]), "=&v"(r[2]), "=&v"(r[3]),
          "=&v"(r[4]), "=&v"(r[5]), "=&v"(r[6]), "=&v"(r[7])
        : "v"(p)
        : "memory");
}

// ---------------------------------------------------------------------------
__global__ void setup_kernel(const float* __restrict__ X,
                             const float* __restrict__ hidden,
                             const float* __restrict__ b_hh,
                             const float* __restrict__ W_out,
                             const float* __restrict__ alpha_w,
                             const float* __restrict__ noise,
                             unsigned short* __restrict__ Xt,
                             float* __restrict__ NB,
                             unsigned short* __restrict__ Wo,
                             unsigned int* __restrict__ Hb0,
                             unsigned int* __restrict__ Hb1)
{
    int idx = blockIdx.x * 256 + threadIdx.x;
    // X [B][T][NIN] -> Xt [T][B][NIN] fp16
    if (idx < B_ * T_ * NIN) {
        int d = idx & 127, rest = idx >> 7;
        int brow = rest & 127, t = rest >> 7;
        Xt[idx] = f16bits(X[((size_t)brow * T_ + t) * NIN + d]);
    }
    if (idx < T_ * NH) {
        int c = idx & (NH - 1);
        NB[idx] = b_hh[c] + noise[idx] * (sqrtf(2.0f / alpha_w[c]) * SIGMA_F);
    }
    if (idx < NIN * NH) Wo[idx] = f16bits(W_out[idx]);
    if (idx < B_ * NH / 2) {
        // slot0 = initial h with gen-0 tag (0); slot1 = poison (tag 1)
        unsigned int lo = f16bits(hidden[idx * 2]);
        unsigned int hi = f16bits(hidden[idx * 2 + 1]);
        Hb0[idx] = (lo | (hi << 16)) & 0x7FFF7FFFu;
        Hb1[idx] = 0x80008000u;
    }
}

// ---------------------------------------------------------------------------
// Persistent RNN: 128 blocks x 256 threads (4 waves, 1 block/CU).
// Roles: m = bx&7 (batch group, XCD-striped), n = bx>>3 (column slice).
__global__ __launch_bounds__(256, 1) void rnn_step_kernel(
    const float* __restrict__ W_hh, const float* __restrict__ W_in,
    const unsigned short* __restrict__ Xt, const float* __restrict__ NB,
    unsigned int* __restrict__ Hb0, unsigned int* __restrict__ Hb1,
    float* __restrict__ hidden_list, float* __restrict__ h_final)
{
    __shared__ unsigned short wtile[64 * 960];    // 122,880 B (chunks 0..29)
    __shared__ unsigned short htile[16 * 1024];   //  32,768 B (group h tile)

    const int tid = threadIdx.x;
    const int m = blockIdx.x & 7;    // batch group (XCD-striped)
    const int n = blockIdx.x >> 3;   // column slice

    // ---- stage W chunks 0..29 into LDS (XOR-swizzled 16B granules) ----
    for (int g = tid; g < 64 * 120; g += 256) {
        int row = g / 120, G = g - row * 120;
        const float* s = W_hh + (size_t)(n * 64 + row) * NH + G * 8;
        half8 h;
        #pragma unroll
        for (int j = 0; j < 8; ++j) h[j] = (_Float16)s[j];
        *(half8*)&wtile[row * 960 + ((G ^ (row & 7)) << 3)] = h;
    }

    const int wave = tid >> 6, lane = tid & 63;
    const int l15 = lane & 15, lk = lane >> 4;
    const int colW = wave * 16 + l15;       // local W row / output col
    const int gcol = n * 64 + colW;         // global hidden col

    // ---- per-lane register B-fragments: W_hh chunks 30,31 + W_in 4 chunks ----
    auto cvt8 = [](const float* s) {
        half8 h;
        #pragma unroll
        for (int j = 0; j < 8; ++j) h[j] = (_Float16)s[j];
        return h;
    };
    half8 bh30 = cvt8(W_hh + (size_t)gcol * NH + 960 + lk * 8);
    half8 bh31 = cvt8(W_hh + (size_t)gcol * NH + 992 + lk * 8);
    half8 bx[4];
    #pragma unroll
    for (int kx = 0; kx < 4; ++kx)
        bx[kx] = cvt8(W_in + (size_t)gcol * NIN + kx * 32 + lk * 8);
    __syncthreads();

    // h staging role: thread (hrow, part); 8 granules G = j*16+part of row hrow
    const int hrow = tid >> 4;       // 0..15
    const int part = tid & 15;

    auto xpart = [&](int t) -> f32x4 {
        f32x4 a = {0.f, 0.f, 0.f, 0.f};
        const int rowA = m * MB + l15;
        const ushort8* xp = (const ushort8*)(Xt + ((size_t)t * B_ + rowA) * NIN) + lk;
        #pragma unroll
        for (int kx = 0; kx < 4; ++kx) {
            half8 av = __builtin_bit_cast(half8, xp[kx * 4]);
            a = __builtin_amdgcn_mfma_f32_16x16x32_f16(av, bx[kx], a, 0, 0, 0);
        }
        return a;
    };

    f32x4 accx = xpart(0);

    for (int t = 0; t < T_; ++t) {
        const u64* hp = (const u64*)((t & 1) ? Hb1 : Hb0)
                        + (size_t)(m * MB + hrow) * 256 + part * 2;
        const unsigned int e32 = ((t >> 1) & 1) ? 0x80008000u : 0u;

        // ---- phase 1: escalating tagged spin ----
        // rounds 0..2: sc0 loads (fast when same-XCD L2-served; cheap
        // L1 hits otherwise). rounds 3+: agent-scope loads (L3-coherent,
        // guaranteed fresh -> progress) with backoff.
        u32x4 r[8];
        int round = 0;
        for (;;) {
            if (round < 3) {
                ld8_sc0(r, hp);
            } else {
                #pragma unroll
                for (int j = 0; j < 8; ++j) {
                    u64 a = ald(hp + (size_t)j * 32);
                    u64 b = ald(hp + (size_t)j * 32 + 1);
                    r[j][0] = (unsigned int)a; r[j][1] = (unsigned int)(a >> 32);
                    r[j][2] = (unsigned int)b; r[j][3] = (unsigned int)(b >> 32);
                }
            }
            unsigned int red = 0;
            #pragma unroll
            for (int j = 0; j < 8; ++j) {
                #pragma unroll
                for (int k = 0; k < 4; ++k) red |= r[j][k] ^ e32;
            }
            if (!(red & 0x80008000u)) break;
            ++round;
            if (round >= 3) __builtin_amdgcn_s_sleep(1);
        }

        __syncthreads();   // prior-iteration htile reads complete (WAR)

        // strip tags, stage to LDS (swizzled granules)
        #pragma unroll
        for (int j = 0; j < 8; ++j) {
            u32x4 w;
            #pragma unroll
            for (int k = 0; k < 4; ++k) w[k] = r[j][k] & 0x7FFF7FFFu;
            int G = j * 16 + part;
            *(half8*)&htile[hrow * 1024 + ((G ^ (hrow & 7)) << 3)] =
                __builtin_bit_cast(half8, w);
        }

        __syncthreads();   // htile ready

        // ---- phase 2: 36 MFMAs (30 LDS-B + 2 reg-B; 4 x-chunks in accx) ----
        f32x4 acc = accx;
        #pragma unroll
        for (int ki = 0; ki < 30; ++ki) {
            int G = 4 * ki + lk;
            half8 av = *(const half8*)&htile[l15 * 1024 + ((G ^ (l15 & 7)) << 3)];
            half8 bv = *(const half8*)&wtile[colW * 960 + ((G ^ (colW & 7)) << 3)];
            acc = __builtin_amdgcn_mfma_f32_16x16x32_f16(av, bv, acc, 0, 0, 0);
        }
        {
            int G = 120 + lk;
            half8 av = *(const half8*)&htile[l15 * 1024 + ((G ^ (l15 & 7)) << 3)];
            acc = __builtin_amdgcn_mfma_f32_16x16x32_f16(av, bh30, acc, 0, 0, 0);
            G = 124 + lk;
            av = *(const half8*)&htile[l15 * 1024 + ((G ^ (l15 & 7)) << 3)];
            acc = __builtin_amdgcn_mfma_f32_16x16x32_f16(av, bh31, acc, 0, 0, 0);
        }

        // ---- bias+noise, relu ----
        const float nb = NB[t * NH + gcol];
        float hv[4];
        #pragma unroll
        for (int r2 = 0; r2 < 4; ++r2) {
            float v = acc[r2] + nb;
            hv[r2] = v > 0.f ? v : 0.f;
        }

        // ---- publish h_{t+1} FIRST (tag in-word; agent store writes
        //      through local L2 -> visible to same-XCD sc0 pollers AND L3) ----
        if (t < T_ - 1) {
            unsigned int* hn = (t & 1) ? Hb0 : Hb1;
            const unsigned int tagb = (((t + 1) >> 1) & 1) ? 0x80008000u : 0u;
            #pragma unroll
            for (int r2 = 0; r2 < 4; ++r2) {
                float other = __shfl_xor(hv[r2], 1);
                if (!(lane & 1)) {
                    unsigned int val = (unsigned int)f16bits(hv[r2]) |
                                       ((unsigned int)f16bits(other) << 16) | tagb;
                    int brow = m * MB + lk * 4 + r2;
                    ast(&hn[(size_t)brow * 512 + (gcol >> 1)], val);
                }
            }
        }

        // ---- off-critical-path: fp32 outputs, next x-part ----
        #pragma unroll
        for (int r2 = 0; r2 < 4; ++r2) {
            int brow = m * MB + lk * 4 + r2;
            hidden_list[((size_t)brow * T_ + t) * NH + gcol] = hv[r2];
        }
        if (t == T_ - 1) {
            #pragma unroll
            for (int r2 = 0; r2 < 4; ++r2) {
                int brow = m * MB + lk * 4 + r2;
                h_final[(size_t)brow * NH + gcol] = hv[r2];
            }
        } else {
            accx = xpart(t + 1);
        }
    }
}

// ---------------------------------------------------------------------------
// Readout: Y[32768,128] = HL[32768,1024](f32->f16) @ Wo^T(f16), fp32 out.
__global__ __launch_bounds__(256, 4) void ygemm_kernel(
    const float* __restrict__ HL, const unsigned short* __restrict__ Wo,
    float* __restrict__ Y)
{
    const int tid = threadIdx.x;
    const int wave = tid >> 6, lane = tid & 63;
    const int l15 = lane & 15, lk = lane >> 4;
    const size_t rowbase = (size_t)blockIdx.x * 64;

    f32x4 acc[4][2] = {};

    #pragma unroll 2
    for (int ki = 0; ki < 32; ++ki) {
        const int k0 = ki * 32 + lk * 8;
        half8 bfr[2];
        #pragma unroll
        for (int nt = 0; nt < 2; ++nt) {
            int ncol = (wave * 2 + nt) * 16 + l15;
            ushort8 braw = *(const ushort8*)(Wo + ncol * NH + k0);
            bfr[nt] = __builtin_bit_cast(half8, braw);
        }
        #pragma unroll
        for (int mt = 0; mt < 4; ++mt) {
            size_t row = rowbase + mt * 16 + l15;
            const float4* ap = (const float4*)(HL + row * NH + k0);
            float4 a0 = ap[0];
            float4 a1 = ap[1];
            half8 a = { (_Float16)a0.x, (_Float16)a0.y, (_Float16)a0.z, (_Float16)a0.w,
                        (_Float16)a1.x, (_Float16)a1.y, (_Float16)a1.z, (_Float16)a1.w };
            #pragma unroll
            for (int nt = 0; nt < 2; ++nt)
                acc[mt][nt] = __builtin_amdgcn_mfma_f32_16x16x32_f16(a, bfr[nt], acc[mt][nt], 0, 0, 0);
        }
    }

    #pragma unroll
    for (int mt = 0; mt < 4; ++mt) {
        #pragma unroll
        for (int nt = 0; nt < 2; ++nt) {
            int ncol = (wave * 2 + nt) * 16 + l15;
            #pragma unroll
            for (int r = 0; r < 4; ++r) {
                size_t row = rowbase + mt * 16 + lk * 4 + r;
                Y[row * NIN + ncol] = acc[mt][nt][r];
            }
        }
    }
}

// ---------------------------------------------------------------------------
extern "C" void kernel_launch(void* const* d_in, const int* in_sizes, int n_in,
                              void* d_out, int out_size, void* d_ws, size_t ws_size,
                              hipStream_t stream)
{
    const float* X      = (const float*)d_in[0];
    const float* hidden = (const float*)d_in[1];
    const float* W_in   = (const float*)d_in[2];
    const float* W_hh   = (const float*)d_in[3];
    const float* b_hh   = (const float*)d_in[4];
    const float* W_out  = (const float*)d_in[5];
    const float* alpha  = (const float*)d_in[6];
    const float* noise  = (const float*)d_in[7];

    char* ws = (char*)d_ws;   // ~10.2 MB
    unsigned short* Xt = (unsigned short*)(ws + OFF_XT);
    float*          NB = (float*)(ws + OFF_NB);
    unsigned short* Wo = (unsigned short*)(ws + OFF_WO);
    unsigned int*  Hb0 = (unsigned int*)(ws + OFF_HB);
    unsigned int*  Hb1 = Hb0 + (size_t)B_ * NH / 2;

    float* hidden_list = (float*)d_out;                                  // [128,256,1024]
    float* output_list = hidden_list + (size_t)B_ * T_ * NH;             // [128,256,128]
    float* h_final     = output_list + (size_t)B_ * T_ * NIN;            // [128,1024]

    setup_kernel<<<(B_ * T_ * NIN + 255) / 256, 256, 0, stream>>>(
        X, hidden, b_hh, W_out, alpha, noise, Xt, NB, Wo, Hb0, Hb1);

    rnn_step_kernel<<<128, 256, 0, stream>>>(
        W_hh, W_in, Xt, NB, Hb0, Hb1, hidden_list, h_final);

    ygemm_kernel<<<(B_ * T_) / 64, 256, 0, stream>>>(
        hidden_list, Wo, output_list);
}